// Round 7
// baseline (385.956 us; speedup 1.0000x reference)
//
#include <hip/hip_runtime.h>
#include <math.h>

#define SEQ 1024
#define DMODEL 768
#define NHEADS 12
#define HDIM 64
#define D3 2304
#define BH 48            // BATCH*NHEADS
#define NTOK 4096        // BATCH*SEQ
#define KTH 104857u      // int(1024*1024*0.1)
#define NBIN 4096        // exact-bf16 hist bins: patterns 14336..18431 (+clamp)
#define BIN0 14336       // bf16 pattern of 2^-15

typedef __bf16 bf16x8 __attribute__((ext_vector_type(8)));
typedef float  f32x4  __attribute__((ext_vector_type(4)));

// swizzled LDS offset (ushort units) for the GEMM core
#define SWZ(row, chunk) ((row) * 32 + (((chunk) ^ (((row) >> 1) & 3)) * 8))

// ---------------- fp32 -> (bf16 hi, bf16 lo) split, RNE ----------------
__device__ __forceinline__ void split1(float x, ushort& h, ushort& l) {
    unsigned b  = __float_as_uint(x);
    unsigned hb = (b + 0x7FFFu + ((b >> 16) & 1u)) >> 16;   // RNE to bf16
    float hf = __uint_as_float(hb << 16);
    float r  = x - hf;
    unsigned rb = __float_as_uint(r);
    unsigned lb = (rb + 0x7FFFu + ((rb >> 16) & 1u)) >> 16;
    h = (ushort)hb; l = (ushort)lb;
}

__device__ __forceinline__ ushort bf16rne(float x) {
    unsigned b = __float_as_uint(x);
    return (ushort)((b + 0x7FFFu + ((b >> 16) & 1u)) >> 16);
}

// ---------------- elementwise split: x -> xh, xl (+ zero hist) ----------------
__global__ __launch_bounds__(256) void k_xsplit(const float* __restrict__ x,
                                                ushort* __restrict__ xh,
                                                ushort* __restrict__ xl, int n,
                                                unsigned* __restrict__ hist) {
    int g = blockIdx.x * 256 + threadIdx.x;
    if (g < BH * NBIN) hist[g] = 0u;
    int i = g * 4;
    if (i >= n) return;
    float4 v = *(const float4*)(x + i);
    ushort4 h, l;
    split1(v.x, h.x, l.x); split1(v.y, h.y, l.y);
    split1(v.z, h.z, l.z); split1(v.w, h.w, l.w);
    *(ushort4*)(xh + i) = h;
    *(ushort4*)(xl + i) = l;
}

// ---------------- transpose + split: W[K][N] -> Wt_h/Wt_l [N][K] ----------------
__global__ __launch_bounds__(256) void k_wsplit(const float* __restrict__ W,
                                                ushort* __restrict__ Wth,
                                                ushort* __restrict__ Wtl,
                                                int K, int N) {
    __shared__ float t[64][65];
    int k0 = blockIdx.y * 64, n0 = blockIdx.x * 64;
    int tid = threadIdx.x;
    int r = tid >> 4, c = (tid & 15) * 4;
#pragma unroll
    for (int u = 0; u < 4; u++) {
        int rr = r + u * 16;
        float4 v = *(const float4*)(W + (size_t)(k0 + rr) * N + n0 + c);
        t[rr][c] = v.x; t[rr][c + 1] = v.y; t[rr][c + 2] = v.z; t[rr][c + 3] = v.w;
    }
    __syncthreads();
    int n = tid >> 2, kc = (tid & 3) * 16;
    ushort hb[16] __attribute__((aligned(16)));
    ushort lb[16] __attribute__((aligned(16)));
#pragma unroll
    for (int j = 0; j < 16; j++) split1(t[kc + j][n], hb[j], lb[j]);
    ushort* dh = Wth + (size_t)(n0 + n) * K + k0 + kc;
    ushort* dl = Wtl + (size_t)(n0 + n) * K + k0 + kc;
    *(uint4*)(dh)     = *(uint4*)&hb[0];
    *(uint4*)(dh + 8) = *(uint4*)&hb[8];
    *(uint4*)(dl)     = *(uint4*)&lb[0];
    *(uint4*)(dl + 8) = *(uint4*)&lb[8];
}

// ======================================================================
// Pipelined bf16x3 GEMM core: BM=64, BN=128, BK=32, 256 thr (r6 core).
// ======================================================================
#define GEMM_CORE_SETUP(Kdim)                                                   \
    __shared__ ushort sA[2][2][64 * 32];                                        \
    __shared__ ushort sB[2][2][128 * 32];                                       \
    int tid = threadIdx.x, lane = tid & 63, wave = tid >> 6;                    \
    int wm = (wave >> 1) * 32, wn = (wave & 1) * 64;                            \
    int l15 = lane & 15, q = lane >> 4;                                         \
    int sr = tid >> 2, sc = tid & 3;                                            \
    const int K = (Kdim);                                                       \
    const ushort* pAh = Ah + (size_t)(m0 + sr) * K + sc * 8;                    \
    const ushort* pAl = Al + (size_t)(m0 + sr) * K + sc * 8;                    \
    const ushort* pBh = Bh + (size_t)(n0 + sr) * K + sc * 8;                    \
    const ushort* pBl = Bl + (size_t)(n0 + sr) * K + sc * 8;                    \
    size_t bstep = (size_t)64 * K;                                              \
    int wA = SWZ(sr, sc), wB2 = SWZ(sr + 64, sc);                               \
    f32x4 acc[2][4] = {};                                                       \
    uint4 rAh = *(const uint4*)(pAh);                                           \
    uint4 rAl = *(const uint4*)(pAl);                                           \
    uint4 rBh0 = *(const uint4*)(pBh);                                          \
    uint4 rBh1 = *(const uint4*)(pBh + bstep);                                  \
    uint4 rBl0 = *(const uint4*)(pBl);                                          \
    uint4 rBl1 = *(const uint4*)(pBl + bstep);                                  \
    *(uint4*)(&sA[0][0][wA])  = rAh;                                            \
    *(uint4*)(&sA[0][1][wA])  = rAl;                                            \
    *(uint4*)(&sB[0][0][wA])  = rBh0;                                           \
    *(uint4*)(&sB[0][0][wB2]) = rBh1;                                           \
    *(uint4*)(&sB[0][1][wA])  = rBl0;                                           \
    *(uint4*)(&sB[0][1][wB2]) = rBl1;                                           \
    __syncthreads();                                                            \
    const int NIT = K / 32;                                                     \
    for (int it = 0; it < NIT; ++it) {                                          \
        int cur = it & 1;                                                       \
        if (it + 1 < NIT) {                                                     \
            int ko = (it + 1) * 32;                                             \
            rAh  = *(const uint4*)(pAh + ko);                                   \
            rAl  = *(const uint4*)(pAl + ko);                                   \
            rBh0 = *(const uint4*)(pBh + ko);                                   \
            rBh1 = *(const uint4*)(pBh + bstep + ko);                           \
            rBl0 = *(const uint4*)(pBl + ko);                                   \
            rBl1 = *(const uint4*)(pBl + bstep + ko);                           \
        }                                                                       \
        bf16x8 fah[2], fal[2], fbh[4], fbl[4];                                  \
        _Pragma("unroll")                                                       \
        for (int mt = 0; mt < 2; mt++) {                                        \
            int rr = wm + mt * 16 + l15;                                        \
            fah[mt] = *(const bf16x8*)(&sA[cur][0][SWZ(rr, q)]);                \
            fal[mt] = *(const bf16x8*)(&sA[cur][1][SWZ(rr, q)]);                \
        }                                                                       \
        _Pragma("unroll")                                                       \
        for (int nt = 0; nt < 4; nt++) {                                        \
            int rr = wn + nt * 16 + l15;                                        \
            fbh[nt] = *(const bf16x8*)(&sB[cur][0][SWZ(rr, q)]);                \
            fbl[nt] = *(const bf16x8*)(&sB[cur][1][SWZ(rr, q)]);                \
        }                                                                       \
        _Pragma("unroll")                                                       \
        for (int mt = 0; mt < 2; mt++)                                          \
            _Pragma("unroll")                                                   \
            for (int nt = 0; nt < 4; nt++) {                                    \
                acc[mt][nt] = __builtin_amdgcn_mfma_f32_16x16x32_bf16(          \
                    fah[mt], fbh[nt], acc[mt][nt], 0, 0, 0);                    \
                acc[mt][nt] = __builtin_amdgcn_mfma_f32_16x16x32_bf16(          \
                    fah[mt], fbl[nt], acc[mt][nt], 0, 0, 0);                    \
                acc[mt][nt] = __builtin_amdgcn_mfma_f32_16x16x32_bf16(          \
                    fal[mt], fbh[nt], acc[mt][nt], 0, 0, 0);                    \
            }                                                                   \
        if (it + 1 < NIT) {                                                     \
            int nxt = cur ^ 1;                                                  \
            *(uint4*)(&sA[nxt][0][wA])  = rAh;                                  \
            *(uint4*)(&sA[nxt][1][wA])  = rAl;                                  \
            *(uint4*)(&sB[nxt][0][wA])  = rBh0;                                 \
            *(uint4*)(&sB[nxt][0][wB2]) = rBh1;                                 \
            *(uint4*)(&sB[nxt][1][wA])  = rBl0;                                 \
            *(uint4*)(&sB[nxt][1][wB2]) = rBl1;                                 \
        }                                                                       \
        __syncthreads();                                                        \
    }

// ---------------- out-proj GEMM: C = A@B + bias (fp32 out) ----------------
__global__ __launch_bounds__(256) void k_gemm_out(
    const ushort* __restrict__ Ah, const ushort* __restrict__ Al,
    const ushort* __restrict__ Bh, const ushort* __restrict__ Bl,
    const float* __restrict__ bias, float* __restrict__ C,
    int M, int N, int Kin) {
    int m0 = blockIdx.y * 64, n0 = blockIdx.x * 128;
    GEMM_CORE_SETUP(Kin)
#pragma unroll
    for (int nt = 0; nt < 4; nt++) {
        int col = n0 + wn + nt * 16 + l15;
        float bv = bias[col];
#pragma unroll
        for (int mt = 0; mt < 2; mt++) {
            int rowb = m0 + wm + mt * 16 + q * 4;
#pragma unroll
            for (int r = 0; r < 4; r++)
                C[(size_t)(rowb + r) * N + col] = acc[mt][nt][r] + bv;
        }
    }
}

// ---------------- QKV GEMM: epilogue writes split Q/K straight + V(hi) transposed
__global__ __launch_bounds__(256) void k_gemm_qkv(
    const ushort* __restrict__ Ah, const ushort* __restrict__ Al,
    const ushort* __restrict__ Bh, const ushort* __restrict__ Bl,
    const float* __restrict__ bias,
    ushort* __restrict__ Qh, ushort* __restrict__ Ql,
    ushort* __restrict__ Kh, ushort* __restrict__ Kl,
    ushort* __restrict__ Vth) {
    int m0 = blockIdx.y * 64, n0 = blockIdx.x * 128;
    GEMM_CORE_SETUP(DMODEL)
    int region = n0 / 768;    // 0=Q, 1=K, 2=V (uniform per block: 128 | 768)
#pragma unroll
    for (int nt = 0; nt < 4; nt++) {
        int col = n0 + wn + nt * 16 + l15;
        float bv = bias[col];
        int cin = col - region * 768;
        int h = cin >> 6, d = cin & 63;
#pragma unroll
        for (int mt = 0; mt < 2; mt++) {
            int rowb = m0 + wm + mt * 16 + q * 4;
            int b = rowb >> 10;
            int s0 = rowb & 1023;
            int bh = b * NHEADS + h;
            if (region == 2) {
                ushort h4[4] __attribute__((aligned(8)));
#pragma unroll
                for (int r = 0; r < 4; r++)
                    h4[r] = bf16rne(acc[mt][nt][r] + bv);
                size_t off = ((size_t)(bh * 64 + d) << 10) + s0;
                *(ushort4*)(Vth + off) = *(ushort4*)h4;
            } else {
                ushort* Ph = region ? Kh : Qh;
                ushort* Pl = region ? Kl : Ql;
                size_t off = ((size_t)((bh << 10) + s0)) * 64 + d;
#pragma unroll
                for (int r = 0; r < 4; r++) {
                    ushort hs, ls;
                    split1(acc[mt][nt][r] + bv, hs, ls);
                    Ph[off + (size_t)r * 64] = hs;
                    Pl[off + (size_t)r * 64] = ls;
                }
            }
        }
    }
}

// ---------------- shist: exact-bf16 histogram of p = bf16(exp(QK^T/8)) --------
// grid (8, 8, 48). Direct-global Q/K fragments. No S/P output at all.
__global__ __launch_bounds__(256) void k_shist(
    const ushort* __restrict__ Qh, const ushort* __restrict__ Ql,
    const ushort* __restrict__ Kh, const ushort* __restrict__ Kl,
    unsigned* __restrict__ hist) {
    __shared__ unsigned lh[NBIN];
    int bh = blockIdx.z;
    int i0 = blockIdx.y * 128, j0 = blockIdx.x * 128;
    int tid = threadIdx.x, lane = tid & 63, wave = tid >> 6;
    int l15 = lane & 15, q = lane >> 4;
    int wm = (wave >> 1) * 64, wn = (wave & 1) * 64;
    for (int i = tid; i < NBIN; i += 256) lh[i] = 0u;

    const ushort* qb  = Qh + (((size_t)bh << 10)) * 64;
    const ushort* qlb = Ql + (((size_t)bh << 10)) * 64;
    const ushort* kb  = Kh + (((size_t)bh << 10)) * 64;
    const ushort* klb = Kl + (((size_t)bh << 10)) * 64;

    f32x4 acc[4][4] = {};
#pragma unroll
    for (int kk = 0; kk < 64; kk += 32) {
        bf16x8 fqh[4], fql[4], fkh[4], fkl[4];
#pragma unroll
        for (int mt = 0; mt < 4; mt++) {
            size_t off = (size_t)(i0 + wm + mt * 16 + l15) * 64 + kk + q * 8;
            fqh[mt] = *(const bf16x8*)(qb + off);
            fql[mt] = *(const bf16x8*)(qlb + off);
        }
#pragma unroll
        for (int nt = 0; nt < 4; nt++) {
            size_t off = (size_t)(j0 + wn + nt * 16 + l15) * 64 + kk + q * 8;
            fkh[nt] = *(const bf16x8*)(kb + off);
            fkl[nt] = *(const bf16x8*)(klb + off);
        }
#pragma unroll
        for (int mt = 0; mt < 4; mt++)
#pragma unroll
            for (int nt = 0; nt < 4; nt++) {
                acc[mt][nt] = __builtin_amdgcn_mfma_f32_16x16x32_bf16(
                    fqh[mt], fkh[nt], acc[mt][nt], 0, 0, 0);
                acc[mt][nt] = __builtin_amdgcn_mfma_f32_16x16x32_bf16(
                    fqh[mt], fkl[nt], acc[mt][nt], 0, 0, 0);
                acc[mt][nt] = __builtin_amdgcn_mfma_f32_16x16x32_bf16(
                    fql[mt], fkh[nt], acc[mt][nt], 0, 0, 0);
            }
    }
    __syncthreads();   // lh zeroed by all before atomics
#pragma unroll
    for (int mt = 0; mt < 4; mt++)
#pragma unroll
        for (int nt = 0; nt < 4; nt++) {
#pragma unroll
            for (int r2 = 0; r2 < 4; r2++) {
                ushort pb = bf16rne(__expf(acc[mt][nt][r2] * 0.125f));
                int ib = (int)pb - BIN0;
                ib = (ib < 0) ? 0 : ((ib > NBIN - 1) ? NBIN - 1 : ib);
                atomicAdd(&lh[ib], 1u);
            }
        }
    __syncthreads();
    for (int i = tid; i < NBIN; i += 256) {
        unsigned cc = lh[i];
        if (cc) atomicAdd(&hist[bh * NBIN + i], cc);
    }
}

// ---------------- select: scan 4096 bins -> exact bf16 threshold pattern -------
__global__ void k_select(const unsigned* __restrict__ hist,
                         unsigned* __restrict__ thrb) {
    int bh = blockIdx.x;
    const unsigned* hrow = hist + bh * NBIN;
    __shared__ unsigned ps[256];
    int tid = threadIdx.x;
    unsigned s = 0;
#pragma unroll
    for (int i = 0; i < 16; i++) s += hrow[tid * 16 + i];
    ps[tid] = s;
    __syncthreads();
    if (tid == 0) {
        unsigned k = KTH, run = 0; int chunk = 255;
        for (int t2 = 0; t2 < 256; t2++) {
            if (run + ps[t2] >= k) { chunk = t2; break; }
            run += ps[t2];
        }
        int d = 15;
        for (int i = 0; i < 16; i++) {
            unsigned v = hrow[chunk * 16 + i];
            if (run + v >= k) { d = i; break; }
            run += v;
        }
        thrb[bh] = (unsigned)(BIN0 + chunk * 16 + d);
    }
}

// ---------------- attn: recompute S^T, mask+exp, PV -> ctx ---------------------
// grid (64, 48): block = 16 i-rows; 4 waves split j into 256-spans; per-wave
// LDS transpose (C-frag -> A-frag) with same-wave waitcnt; cross-wave reduce.
__global__ __launch_bounds__(256) void k_attn(
    const ushort* __restrict__ Qh, const ushort* __restrict__ Ql,
    const ushort* __restrict__ Kh, const ushort* __restrict__ Kl,
    const ushort* __restrict__ Vth,
    const unsigned* __restrict__ thrb,
    ushort* __restrict__ ctxh, ushort* __restrict__ ctxl) {
    __shared__ ushort sS[4 * 16 * 36];   // per-wave transpose buffers (4.6 KB)
    __shared__ float sred[4 * 1280];     // cross-wave reduction (20 KB)
    int bh = blockIdx.y;
    int b = bh / NHEADS, h = bh % NHEADS;
    int lane = threadIdx.x & 63, wave = threadIdx.x >> 6;
    int l15 = lane & 15, q = lane >> 4;
    int ibase = blockIdx.x * 16;
    unsigned t = thrb[bh];

    // loop-invariant Q fragments (B-operand of S^T): lane n = i = l15
    size_t qrow = ((size_t)(bh * 1024 + ibase + l15)) * 64;
    bf16x8 fq_h[2], fq_l[2];
    fq_h[0] = *(const bf16x8*)(Qh + qrow + q * 8);
    fq_h[1] = *(const bf16x8*)(Qh + qrow + 32 + q * 8);
    fq_l[0] = *(const bf16x8*)(Ql + qrow + q * 8);
    fq_l[1] = *(const bf16x8*)(Ql + qrow + 32 + q * 8);

    const ushort* kb  = Kh + ((size_t)(bh << 10)) * 64;
    const ushort* klb = Kl + ((size_t)(bh << 10)) * 64;
    const ushort* vh0 = Vth + ((size_t)bh << 16);   // [64][1024]
    ushort* sw = sS + wave * (16 * 36);

    f32x4 acc[4] = {};
    f32x4 lacc = {};
    uint4 onesu = {0x3F803F80u, 0x3F803F80u, 0x3F803F80u, 0x3F803F80u};
    bf16x8 ones = *(bf16x8*)&onesu;

    int jw = wave * 256;
    for (int jc = jw; jc < jw + 256; jc += 32) {
        // two 16x16 S^T tiles (A = K row j, B = Q row i); same term order as k_shist
#pragma unroll
        for (int jt = 0; jt < 2; jt++) {
            const ushort* krow  = kb  + (size_t)(jc + jt * 16 + l15) * 64;
            const ushort* krowl = klb + (size_t)(jc + jt * 16 + l15) * 64;
            f32x4 s = {};
#pragma unroll
            for (int kk = 0; kk < 2; kk++) {
                bf16x8 fkh = *(const bf16x8*)(krow + kk * 32 + q * 8);
                bf16x8 fkl = *(const bf16x8*)(krowl + kk * 32 + q * 8);
                s = __builtin_amdgcn_mfma_f32_16x16x32_bf16(fkh, fq_h[kk], s, 0, 0, 0);
                s = __builtin_amdgcn_mfma_f32_16x16x32_bf16(fkl, fq_h[kk], s, 0, 0, 0);
                s = __builtin_amdgcn_mfma_f32_16x16x32_bf16(fkh, fq_l[kk], s, 0, 0, 0);
            }
            // p = bf16(exp(s/8)), mask <= thr, pack 4 contiguous j -> b64 LDS write
            ushort pb4[4] __attribute__((aligned(8)));
#pragma unroll
            for (int r = 0; r < 4; r++) {
                ushort pbv = bf16rne(__expf(s[r] * 0.125f));
                pb4[r] = (pbv <= t) ? (ushort)0 : pbv;
            }
            *(ushort4*)(sw + l15 * 36 + jt * 16 + q * 4) = *(ushort4*)pb4;
        }
        __asm__ volatile("s_waitcnt lgkmcnt(0)" ::: "memory");  // same-wave LDS RAW
        bf16x8 pa = *(const bf16x8*)(sw + l15 * 36 + q * 8);    // A-frag: i=l15, j=q*8..
#pragma unroll
        for (int nt = 0; nt < 4; nt++) {
            bf16x8 fvh = *(const bf16x8*)(vh0 + (size_t)(nt * 16 + l15) * 1024 + jc + q * 8);
            acc[nt] = __builtin_amdgcn_mfma_f32_16x16x32_bf16(pa, fvh, acc[nt], 0, 0, 0);
        }
        lacc = __builtin_amdgcn_mfma_f32_16x16x32_bf16(pa, ones, lacc, 0, 0, 0);
    }
    // cross-wave reduce over j-quarters
    float* my = sred + wave * 1280;
#pragma unroll
    for (int nt = 0; nt < 4; nt++)
#pragma unroll
        for (int r = 0; r < 4; r++)
            my[(nt * 4 + r) * 64 + lane] = acc[nt][r];
#pragma unroll
    for (int r = 0; r < 4; r++)
        my[(16 + r) * 64 + lane] = lacc[r];
    __syncthreads();
    for (int f = threadIdx.x; f < 1280; f += 256)
        sred[f] = sred[f] + sred[1280 + f] + sred[2560 + f] + sred[3840 + f];
    __syncthreads();
#pragma unroll
    for (int r = 0; r < 4; r++) {
        int i = ibase + q * 4 + r;
        float l = sred[(16 + r) * 64 + lane];
        float v = sred[(wave * 4 + r) * 64 + lane];
        int d = wave * 16 + l15;
        ushort hs, ls;
        split1(v / l, hs, ls);
        size_t off = ((size_t)(b * SEQ + i)) * DMODEL + h * 64 + d;
        ctxh[off] = hs;
        ctxl[off] = ls;
    }
}

extern "C" void kernel_launch(void* const* d_in, const int* in_sizes, int n_in,
                              void* d_out, int out_size, void* d_ws, size_t ws_size,
                              hipStream_t stream) {
    const float* x    = (const float*)d_in[0];
    const float* Wqkv = (const float*)d_in[1];
    const float* bqkv = (const float*)d_in[2];
    const float* Wout = (const float*)d_in[3];
    const float* bout = (const float*)d_in[4];
    float* out = (float*)d_out;

    char* ws = (char*)d_ws;
    ushort* Qh     = (ushort*)(ws + 0);          //  6,291,456
    ushort* Ql     = (ushort*)(ws + 6291456);
    ushort* Kh     = (ushort*)(ws + 12582912);
    ushort* Kl     = (ushort*)(ws + 18874368);
    ushort* Vth    = (ushort*)(ws + 25165824);   //  6,291,456 (hi only)
    ushort* ctxh   = (ushort*)(ws + 31457280);
    ushort* ctxl   = (ushort*)(ws + 37748736);
    ushort* xh     = (ushort*)(ws + 44040192);
    ushort* xl     = (ushort*)(ws + 50331648);
    ushort* Wqkvth = (ushort*)(ws + 56623104);   //  3,538,944
    ushort* Wqkvtl = (ushort*)(ws + 60162048);
    ushort* Woutth = (ushort*)(ws + 63700992);   //  1,179,648
    ushort* Wouttl = (ushort*)(ws + 64880640);
    unsigned* hist = (unsigned*)(ws + 66060288); //  786,432 (48 x 4096 u32)
    unsigned* thrb = (unsigned*)(ws + 66846720); //  192

    // split x (+ zero hist: 48*4096 = 196608 <= 786432 threads)
    k_xsplit<<<NTOK * DMODEL / 1024, 256, 0, stream>>>(x, xh, xl, NTOK * DMODEL, hist);
    k_wsplit<<<dim3(D3 / 64, DMODEL / 64), 256, 0, stream>>>(Wqkv, Wqkvth, Wqkvtl, DMODEL, D3);
    k_gemm_qkv<<<dim3(D3 / 128, NTOK / 64), 256, 0, stream>>>(
        xh, xl, Wqkvth, Wqkvtl, bqkv, Qh, Ql, Kh, Kl, Vth);
    // exact-bf16 histogram of p in ONE pass (no S/P materialization)
    k_shist<<<dim3(8, 8, BH), 256, 0, stream>>>(Qh, Ql, Kh, Kl, hist);
    k_select<<<BH, 256, 0, stream>>>(hist, thrb);
    // fused recompute + mask + PV
    k_attn<<<dim3(64, BH), 256, 0, stream>>>(Qh, Ql, Kh, Kl, Vth, thrb, ctxh, ctxl);
    // out = ctx @ W_out + b_out
    k_wsplit<<<dim3(DMODEL / 64, DMODEL / 64), 256, 0, stream>>>(Wout, Woutth, Wouttl, DMODEL, DMODEL);
    k_gemm_out<<<dim3(DMODEL / 128, NTOK / 64), 256, 0, stream>>>(
        ctxh, ctxl, Woutth, Wouttl, bout, out, NTOK, DMODEL, DMODEL);
}

// Round 8
// 323.067 us; speedup vs baseline: 1.1947x; 1.1947x over previous
//
#include <hip/hip_runtime.h>
#include <math.h>

#define SEQ 1024
#define DMODEL 768
#define NHEADS 12
#define HDIM 64
#define D3 2304
#define BH 48            // BATCH*NHEADS
#define NTOK 4096        // BATCH*SEQ
#define KTH 104857u      // int(1024*1024*0.1)
#define NBIN 4096        // exact-bf16 hist: patterns 14336..18431 (full mantissa)
#define BIN0 14336       // bf16 pattern of 2^-15

typedef __bf16 bf16x8 __attribute__((ext_vector_type(8)));
typedef float  f32x4  __attribute__((ext_vector_type(4)));

// swizzled LDS offset (ushort units) for the GEMM core
#define SWZ(row, chunk) ((row) * 32 + (((chunk) ^ (((row) >> 1) & 3)) * 8))

// ---------------- fp32 -> (bf16 hi, bf16 lo) split, RNE ----------------
__device__ __forceinline__ void split1(float x, ushort& h, ushort& l) {
    unsigned b  = __float_as_uint(x);
    unsigned hb = (b + 0x7FFFu + ((b >> 16) & 1u)) >> 16;   // RNE to bf16
    float hf = __uint_as_float(hb << 16);
    float r  = x - hf;
    unsigned rb = __float_as_uint(r);
    unsigned lb = (rb + 0x7FFFu + ((rb >> 16) & 1u)) >> 16;
    h = (ushort)hb; l = (ushort)lb;
}

__device__ __forceinline__ ushort bf16rne(float x) {
    unsigned b = __float_as_uint(x);
    return (ushort)((b + 0x7FFFu + ((b >> 16) & 1u)) >> 16);
}

// ---------------- elementwise split: x -> xh, xl (+ zero hist) ----------------
__global__ __launch_bounds__(256) void k_xsplit(const float* __restrict__ x,
                                                ushort* __restrict__ xh,
                                                ushort* __restrict__ xl, int n,
                                                unsigned* __restrict__ hist) {
    int g = blockIdx.x * 256 + threadIdx.x;
    if (g < BH * NBIN) hist[g] = 0u;
    int i = g * 4;
    if (i >= n) return;
    float4 v = *(const float4*)(x + i);
    ushort4 h, l;
    split1(v.x, h.x, l.x); split1(v.y, h.y, l.y);
    split1(v.z, h.z, l.z); split1(v.w, h.w, l.w);
    *(ushort4*)(xh + i) = h;
    *(ushort4*)(xl + i) = l;
}

// ---------------- transpose + split: W[K][N] -> Wt_h/Wt_l [N][K] ----------------
__global__ __launch_bounds__(256) void k_wsplit(const float* __restrict__ W,
                                                ushort* __restrict__ Wth,
                                                ushort* __restrict__ Wtl,
                                                int K, int N) {
    __shared__ float t[64][65];
    int k0 = blockIdx.y * 64, n0 = blockIdx.x * 64;
    int tid = threadIdx.x;
    int r = tid >> 4, c = (tid & 15) * 4;
#pragma unroll
    for (int u = 0; u < 4; u++) {
        int rr = r + u * 16;
        float4 v = *(const float4*)(W + (size_t)(k0 + rr) * N + n0 + c);
        t[rr][c] = v.x; t[rr][c + 1] = v.y; t[rr][c + 2] = v.z; t[rr][c + 3] = v.w;
    }
    __syncthreads();
    int n = tid >> 2, kc = (tid & 3) * 16;
    ushort hb[16] __attribute__((aligned(16)));
    ushort lb[16] __attribute__((aligned(16)));
#pragma unroll
    for (int j = 0; j < 16; j++) split1(t[kc + j][n], hb[j], lb[j]);
    ushort* dh = Wth + (size_t)(n0 + n) * K + k0 + kc;
    ushort* dl = Wtl + (size_t)(n0 + n) * K + k0 + kc;
    *(uint4*)(dh)     = *(uint4*)&hb[0];
    *(uint4*)(dh + 8) = *(uint4*)&hb[8];
    *(uint4*)(dl)     = *(uint4*)&lb[0];
    *(uint4*)(dl + 8) = *(uint4*)&lb[8];
}

// ======================================================================
// Pipelined bf16x3 GEMM core: BM=64, BN=128, BK=32, 256 thr (r6 core).
// ======================================================================
#define GEMM_CORE_SETUP(Kdim)                                                   \
    __shared__ ushort sA[2][2][64 * 32];                                        \
    __shared__ ushort sB[2][2][128 * 32];                                       \
    int tid = threadIdx.x, lane = tid & 63, wave = tid >> 6;                    \
    int wm = (wave >> 1) * 32, wn = (wave & 1) * 64;                            \
    int l15 = lane & 15, q = lane >> 4;                                         \
    int sr = tid >> 2, sc = tid & 3;                                            \
    const int K = (Kdim);                                                       \
    const ushort* pAh = Ah + (size_t)(m0 + sr) * K + sc * 8;                    \
    const ushort* pAl = Al + (size_t)(m0 + sr) * K + sc * 8;                    \
    const ushort* pBh = Bh + (size_t)(n0 + sr) * K + sc * 8;                    \
    const ushort* pBl = Bl + (size_t)(n0 + sr) * K + sc * 8;                    \
    size_t bstep = (size_t)64 * K;                                              \
    int wA = SWZ(sr, sc), wB2 = SWZ(sr + 64, sc);                               \
    f32x4 acc[2][4] = {};                                                       \
    uint4 rAh = *(const uint4*)(pAh);                                           \
    uint4 rAl = *(const uint4*)(pAl);                                           \
    uint4 rBh0 = *(const uint4*)(pBh);                                          \
    uint4 rBh1 = *(const uint4*)(pBh + bstep);                                  \
    uint4 rBl0 = *(const uint4*)(pBl);                                          \
    uint4 rBl1 = *(const uint4*)(pBl + bstep);                                  \
    *(uint4*)(&sA[0][0][wA])  = rAh;                                            \
    *(uint4*)(&sA[0][1][wA])  = rAl;                                            \
    *(uint4*)(&sB[0][0][wA])  = rBh0;                                           \
    *(uint4*)(&sB[0][0][wB2]) = rBh1;                                           \
    *(uint4*)(&sB[0][1][wA])  = rBl0;                                           \
    *(uint4*)(&sB[0][1][wB2]) = rBl1;                                           \
    __syncthreads();                                                            \
    const int NIT = K / 32;                                                     \
    for (int it = 0; it < NIT; ++it) {                                          \
        int cur = it & 1;                                                       \
        if (it + 1 < NIT) {                                                     \
            int ko = (it + 1) * 32;                                             \
            rAh  = *(const uint4*)(pAh + ko);                                   \
            rAl  = *(const uint4*)(pAl + ko);                                   \
            rBh0 = *(const uint4*)(pBh + ko);                                   \
            rBh1 = *(const uint4*)(pBh + bstep + ko);                           \
            rBl0 = *(const uint4*)(pBl + ko);                                   \
            rBl1 = *(const uint4*)(pBl + bstep + ko);                           \
        }                                                                       \
        bf16x8 fah[2], fal[2], fbh[4], fbl[4];                                  \
        _Pragma("unroll")                                                       \
        for (int mt = 0; mt < 2; mt++) {                                        \
            int rr = wm + mt * 16 + l15;                                        \
            fah[mt] = *(const bf16x8*)(&sA[cur][0][SWZ(rr, q)]);                \
            fal[mt] = *(const bf16x8*)(&sA[cur][1][SWZ(rr, q)]);                \
        }                                                                       \
        _Pragma("unroll")                                                       \
        for (int nt = 0; nt < 4; nt++) {                                        \
            int rr = wn + nt * 16 + l15;                                        \
            fbh[nt] = *(const bf16x8*)(&sB[cur][0][SWZ(rr, q)]);                \
            fbl[nt] = *(const bf16x8*)(&sB[cur][1][SWZ(rr, q)]);                \
        }                                                                       \
        _Pragma("unroll")                                                       \
        for (int mt = 0; mt < 2; mt++)                                          \
            _Pragma("unroll")                                                   \
            for (int nt = 0; nt < 4; nt++) {                                    \
                acc[mt][nt] = __builtin_amdgcn_mfma_f32_16x16x32_bf16(          \
                    fah[mt], fbh[nt], acc[mt][nt], 0, 0, 0);                    \
                acc[mt][nt] = __builtin_amdgcn_mfma_f32_16x16x32_bf16(          \
                    fah[mt], fbl[nt], acc[mt][nt], 0, 0, 0);                    \
                acc[mt][nt] = __builtin_amdgcn_mfma_f32_16x16x32_bf16(          \
                    fal[mt], fbh[nt], acc[mt][nt], 0, 0, 0);                    \
            }                                                                   \
        if (it + 1 < NIT) {                                                     \
            int nxt = cur ^ 1;                                                  \
            *(uint4*)(&sA[nxt][0][wA])  = rAh;                                  \
            *(uint4*)(&sA[nxt][1][wA])  = rAl;                                  \
            *(uint4*)(&sB[nxt][0][wA])  = rBh0;                                 \
            *(uint4*)(&sB[nxt][0][wB2]) = rBh1;                                 \
            *(uint4*)(&sB[nxt][1][wA])  = rBl0;                                 \
            *(uint4*)(&sB[nxt][1][wB2]) = rBl1;                                 \
        }                                                                       \
        __syncthreads();                                                        \
    }

// ---------------- out-proj GEMM: C = A@B + bias (fp32 out) ----------------
__global__ __launch_bounds__(256) void k_gemm_out(
    const ushort* __restrict__ Ah, const ushort* __restrict__ Al,
    const ushort* __restrict__ Bh, const ushort* __restrict__ Bl,
    const float* __restrict__ bias, float* __restrict__ C,
    int M, int N, int Kin) {
    int m0 = blockIdx.y * 64, n0 = blockIdx.x * 128;
    GEMM_CORE_SETUP(Kin)
#pragma unroll
    for (int nt = 0; nt < 4; nt++) {
        int col = n0 + wn + nt * 16 + l15;
        float bv = bias[col];
#pragma unroll
        for (int mt = 0; mt < 2; mt++) {
            int rowb = m0 + wm + mt * 16 + q * 4;
#pragma unroll
            for (int r = 0; r < 4; r++)
                C[(size_t)(rowb + r) * N + col] = acc[mt][nt][r] + bv;
        }
    }
}

// ---------------- QKV GEMM: epilogue writes split Q/K straight + V(hi) transposed
__global__ __launch_bounds__(256) void k_gemm_qkv(
    const ushort* __restrict__ Ah, const ushort* __restrict__ Al,
    const ushort* __restrict__ Bh, const ushort* __restrict__ Bl,
    const float* __restrict__ bias,
    ushort* __restrict__ Qh, ushort* __restrict__ Ql,
    ushort* __restrict__ Kh, ushort* __restrict__ Kl,
    ushort* __restrict__ Vth) {
    int m0 = blockIdx.y * 64, n0 = blockIdx.x * 128;
    GEMM_CORE_SETUP(DMODEL)
    int region = n0 / 768;    // 0=Q, 1=K, 2=V (uniform per block: 128 | 768)
#pragma unroll
    for (int nt = 0; nt < 4; nt++) {
        int col = n0 + wn + nt * 16 + l15;
        float bv = bias[col];
        int cin = col - region * 768;
        int h = cin >> 6, d = cin & 63;
#pragma unroll
        for (int mt = 0; mt < 2; mt++) {
            int rowb = m0 + wm + mt * 16 + q * 4;
            int b = rowb >> 10;
            int s0 = rowb & 1023;
            int bh = b * NHEADS + h;
            if (region == 2) {
                ushort h4[4] __attribute__((aligned(8)));
#pragma unroll
                for (int r = 0; r < 4; r++)
                    h4[r] = bf16rne(acc[mt][nt][r] + bv);
                size_t off = ((size_t)(bh * 64 + d) << 10) + s0;
                *(ushort4*)(Vth + off) = *(ushort4*)h4;
            } else {
                ushort* Ph = region ? Kh : Qh;
                ushort* Pl = region ? Kl : Ql;
                size_t off = ((size_t)((bh << 10) + s0)) * 64 + d;
#pragma unroll
                for (int r = 0; r < 4; r++) {
                    ushort hs, ls;
                    split1(acc[mt][nt][r] + bv, hs, ls);
                    Ph[off + (size_t)r * 64] = hs;
                    Pl[off + (size_t)r * 64] = ls;
                }
            }
        }
    }
}

// ---------------- scores: P = bf16(exp(QK^T/8)) + fused EXACT 4096-bin hist ----
// grid (8, 8, 48). Direct-global Q/K fragments; LDS for P transpose + hist.
__global__ __launch_bounds__(256) void k_scores(
    const ushort* __restrict__ Qh, const ushort* __restrict__ Ql,
    const ushort* __restrict__ Kh, const ushort* __restrict__ Kl,
    ushort* __restrict__ P, unsigned* __restrict__ hist) {
    __shared__ ushort sP[128 * 132];
    __shared__ unsigned lh[NBIN];
    int bh = blockIdx.z;
    int i0 = blockIdx.y * 128, j0 = blockIdx.x * 128;
    int tid = threadIdx.x, lane = tid & 63, wave = tid >> 6;
    int l15 = lane & 15, q = lane >> 4;
    int wm = (wave >> 1) * 64, wn = (wave & 1) * 64;
    for (int i = tid; i < NBIN; i += 256) lh[i] = 0u;

    const ushort* qb  = Qh + (((size_t)bh << 10)) * 64;
    const ushort* qlb = Ql + (((size_t)bh << 10)) * 64;
    const ushort* kb  = Kh + (((size_t)bh << 10)) * 64;
    const ushort* klb = Kl + (((size_t)bh << 10)) * 64;

    f32x4 acc[4][4] = {};
#pragma unroll
    for (int kk = 0; kk < 64; kk += 32) {
        bf16x8 fqh[4], fql[4], fkh[4], fkl[4];
#pragma unroll
        for (int mt = 0; mt < 4; mt++) {
            size_t off = (size_t)(i0 + wm + mt * 16 + l15) * 64 + kk + q * 8;
            fqh[mt] = *(const bf16x8*)(qb + off);
            fql[mt] = *(const bf16x8*)(qlb + off);
        }
#pragma unroll
        for (int nt = 0; nt < 4; nt++) {
            size_t off = (size_t)(j0 + wn + nt * 16 + l15) * 64 + kk + q * 8;
            fkh[nt] = *(const bf16x8*)(kb + off);
            fkl[nt] = *(const bf16x8*)(klb + off);
        }
#pragma unroll
        for (int mt = 0; mt < 4; mt++)
#pragma unroll
            for (int nt = 0; nt < 4; nt++) {
                acc[mt][nt] = __builtin_amdgcn_mfma_f32_16x16x32_bf16(
                    fqh[mt], fkh[nt], acc[mt][nt], 0, 0, 0);
                acc[mt][nt] = __builtin_amdgcn_mfma_f32_16x16x32_bf16(
                    fqh[mt], fkl[nt], acc[mt][nt], 0, 0, 0);
                acc[mt][nt] = __builtin_amdgcn_mfma_f32_16x16x32_bf16(
                    fql[mt], fkh[nt], acc[mt][nt], 0, 0, 0);
            }
    }
    __syncthreads();   // lh zeroed by all before atomics
    // epilogue: p = bf16(exp(s/8)); LDS transpose + full-mantissa histogram
#pragma unroll
    for (int mt = 0; mt < 4; mt++)
#pragma unroll
        for (int nt = 0; nt < 4; nt++) {
            int jj = wn + nt * 16 + l15;
            int ib = wm + mt * 16 + q * 4;
#pragma unroll
            for (int r2 = 0; r2 < 4; r2++) {
                ushort pb = bf16rne(__expf(acc[mt][nt][r2] * 0.125f));
                sP[(ib + r2) * 132 + jj] = pb;
                int bin = (int)pb - BIN0;
                bin = (bin < 0) ? 0 : ((bin > NBIN - 1) ? NBIN - 1 : bin);
                atomicAdd(&lh[bin], 1u);
            }
        }
    __syncthreads();
    // coalesced P write-out: 2 threads per row
    int rloc = tid >> 1;
    int ch = (tid & 1) * 64;
    ushort* dst = P + ((size_t)bh << 20) + (size_t)(i0 + rloc) * 1024 + j0 + ch;
    const ushort* src = sP + rloc * 132 + ch;
#pragma unroll
    for (int c = 0; c < 8; c++)
        *(uint4*)(dst + c * 8) = *(const uint4*)(src + c * 8);
    for (int i = tid; i < NBIN; i += 256) {
        unsigned cc = lh[i];
        if (cc) atomicAdd(&hist[bh * NBIN + i], cc);
    }
}

// ---------------- select: scan 4096 bins -> exact bf16 threshold pattern -------
__global__ void k_select(const unsigned* __restrict__ hist,
                         unsigned* __restrict__ thrb) {
    int bh = blockIdx.x;
    const unsigned* hrow = hist + bh * NBIN;
    __shared__ unsigned ps[256];
    int tid = threadIdx.x;
    unsigned s = 0;
#pragma unroll
    for (int i = 0; i < 16; i++) s += hrow[tid * 16 + i];
    ps[tid] = s;
    __syncthreads();
    if (tid == 0) {
        unsigned k = KTH, run = 0; int chunk = 255;
        for (int t2 = 0; t2 < 256; t2++) {
            if (run + ps[t2] >= k) { chunk = t2; break; }
            run += ps[t2];
        }
        int d = 15;
        for (int i = 0; i < 16; i++) {
            unsigned v = hrow[chunk * 16 + i];
            if (run + v >= k) { d = i; break; }
            run += v;
        }
        thrb[bh] = (unsigned)(BIN0 + chunk * 16 + d);
    }
}

// ---------------- PV: ctx = (masked P) @ Vh / rowsum ---------------------------
// grid (64, 48): 16 rows per block; 4 waves split the j-axis (256 each);
// LDS cross-wave reduction.
__global__ __launch_bounds__(256) void k_pv(const ushort* __restrict__ P,
                                            const ushort* __restrict__ Vth,
                                            const unsigned* __restrict__ thrb,
                                            ushort* __restrict__ ctxh,
                                            ushort* __restrict__ ctxl) {
    __shared__ float sred[4 * 1280];   // [wave][ (acc_idx*4+r)*64 + lane ]
    int bh = blockIdx.y;
    int b = bh / NHEADS, h = bh % NHEADS;
    int lane = threadIdx.x & 63, wave = threadIdx.x >> 6;
    int l15 = lane & 15, q = lane >> 4;
    int ibase = blockIdx.x * 16;
    unsigned t = thrb[bh];
    const ushort* prow = P + ((size_t)bh << 20) + (size_t)(ibase + l15) * 1024 + q * 8;
    const ushort* vh0 = Vth + ((size_t)bh << 16);   // [64][1024]
    f32x4 acc[4] = {};
    f32x4 lacc = {};
    uint4 onesu = {0x3F803F80u, 0x3F803F80u, 0x3F803F80u, 0x3F803F80u};
    bf16x8 ones = *(bf16x8*)&onesu;
    int jw = wave * 256;
#pragma unroll 2
    for (int j0 = jw; j0 < jw + 256; j0 += 32) {
        uint4 a = *(const uint4*)(prow + j0);
        unsigned* w = (unsigned*)&a;
#pragma unroll
        for (int e = 0; e < 4; e++) {
            unsigned lo = w[e] & 0xFFFFu, hi = w[e] >> 16;
            lo = (lo <= t) ? 0u : lo;
            hi = (hi <= t) ? 0u : hi;
            w[e] = lo | (hi << 16);
        }
        bf16x8 pa = *(bf16x8*)&a;
#pragma unroll
        for (int nt = 0; nt < 4; nt++) {
            size_t off = (size_t)(nt * 16 + l15) * 1024 + j0 + q * 8;
            bf16x8 fvh = *(const bf16x8*)(vh0 + off);
            acc[nt] = __builtin_amdgcn_mfma_f32_16x16x32_bf16(pa, fvh, acc[nt], 0, 0, 0);
        }
        lacc = __builtin_amdgcn_mfma_f32_16x16x32_bf16(pa, ones, lacc, 0, 0, 0);
    }
    float* my = sred + wave * 1280;
#pragma unroll
    for (int nt = 0; nt < 4; nt++)
#pragma unroll
        for (int r = 0; r < 4; r++)
            my[(nt * 4 + r) * 64 + lane] = acc[nt][r];
#pragma unroll
    for (int r = 0; r < 4; r++)
        my[(16 + r) * 64 + lane] = lacc[r];
    __syncthreads();
    for (int f = threadIdx.x; f < 1280; f += 256)
        sred[f] = sred[f] + sred[1280 + f] + sred[2560 + f] + sred[3840 + f];
    __syncthreads();
#pragma unroll
    for (int r = 0; r < 4; r++) {
        int i = ibase + q * 4 + r;
        float l = sred[(16 + r) * 64 + lane];
        float v = sred[(wave * 4 + r) * 64 + lane];
        int d = wave * 16 + l15;
        ushort hs, ls;
        split1(v / l, hs, ls);
        size_t off = ((size_t)(b * SEQ + i)) * DMODEL + h * 64 + d;
        ctxh[off] = hs;
        ctxl[off] = ls;
    }
}

extern "C" void kernel_launch(void* const* d_in, const int* in_sizes, int n_in,
                              void* d_out, int out_size, void* d_ws, size_t ws_size,
                              hipStream_t stream) {
    const float* x    = (const float*)d_in[0];
    const float* Wqkv = (const float*)d_in[1];
    const float* bqkv = (const float*)d_in[2];
    const float* Wout = (const float*)d_in[3];
    const float* bout = (const float*)d_in[4];
    float* out = (float*)d_out;

    char* ws = (char*)d_ws;
    // persistent layout
    ushort* Qh  = (ushort*)(ws + 0);                 //  6,291,456
    ushort* Ql  = (ushort*)(ws + 6291456);
    ushort* Kh  = (ushort*)(ws + 12582912);
    ushort* Kl  = (ushort*)(ws + 18874368);
    ushort* Vth = (ushort*)(ws + 25165824);          //  6,291,456 (hi only)
    ushort* P   = (ushort*)(ws + 37748736);          // 100,663,296 -> ends 138,412,032
    ushort* ctxh = (ushort*)(ws + 239075328);        //  6,291,456
    ushort* ctxl = (ushort*)(ws + 245366784);        // ends 251,658,240
    unsigned* hist = (unsigned*)(ws + 251658240);    // 48*4096*4 = 786,432
    unsigned* thrb = (unsigned*)(ws + 252444672);    // 192
    // overlays inside P region (dead until k_scores writes P):
    ushort* xh     = (ushort*)(ws + 37748736);
    ushort* xl     = (ushort*)(ws + 37748736 + 6291456);
    ushort* Wqkvth = (ushort*)(ws + 37748736 + 12582912);
    ushort* Wqkvtl = (ushort*)(ws + 37748736 + 16121856);
    // Wout split overlays P (dead after k_pv):
    ushort* Woutth = (ushort*)(ws + 37748736);
    ushort* Wouttl = (ushort*)(ws + 37748736 + 1179648);

    // split x (+ zero hist: 196,608 slots <= 786,432 threads)
    k_xsplit<<<NTOK * DMODEL / 1024, 256, 0, stream>>>(x, xh, xl, NTOK * DMODEL, hist);
    k_wsplit<<<dim3(D3 / 64, DMODEL / 64), 256, 0, stream>>>(Wqkv, Wqkvth, Wqkvtl, DMODEL, D3);
    k_gemm_qkv<<<dim3(D3 / 128, NTOK / 64), 256, 0, stream>>>(
        xh, xl, Wqkvth, Wqkvtl, bqkv, Qh, Ql, Kh, Kl, Vth);
    // P = bf16(exp(QK^T/8)) + fused exact 4096-bin histogram
    k_scores<<<dim3(8, 8, BH), 256, 0, stream>>>(Qh, Ql, Kh, Kl, P, hist);
    k_select<<<BH, 256, 0, stream>>>(hist, thrb);
    // ctx = masked-softmax(P) @ V
    k_pv<<<dim3(64, BH), 256, 0, stream>>>(P, Vth, thrb, ctxh, ctxl);
    // out = ctx @ W_out + b_out
    k_wsplit<<<dim3(DMODEL / 64, DMODEL / 64), 256, 0, stream>>>(Wout, Woutth, Wouttl, DMODEL, DMODEL);
    k_gemm_out<<<dim3(DMODEL / 128, NTOK / 64), 256, 0, stream>>>(
        ctxh, ctxl, Woutth, Wouttl, bout, out, NTOK, DMODEL, DMODEL);
}

// Round 9
// 313.069 us; speedup vs baseline: 1.2328x; 1.0319x over previous
//
#include <hip/hip_runtime.h>
#include <math.h>

#define SEQ 1024
#define DMODEL 768
#define NHEADS 12
#define HDIM 64
#define D3 2304
#define BH 48            // BATCH*NHEADS
#define NTOK 4096        // BATCH*SEQ
#define KTH 104857u      // int(1024*1024*0.1)
#define NBIN 4096        // exact-bf16 hist: patterns 14336..18431 (full mantissa)
#define BIN0 14336       // bf16 pattern of 2^-15

typedef __bf16 bf16x8 __attribute__((ext_vector_type(8)));
typedef float  f32x4  __attribute__((ext_vector_type(4)));

// swizzled LDS offset (ushort units) for the GEMM core
#define SWZ(row, chunk) ((row) * 32 + (((chunk) ^ (((row) >> 1) & 3)) * 8))

// ---------------- fp32 -> (bf16 hi, bf16 lo) split, RNE ----------------
__device__ __forceinline__ void split1(float x, ushort& h, ushort& l) {
    unsigned b  = __float_as_uint(x);
    unsigned hb = (b + 0x7FFFu + ((b >> 16) & 1u)) >> 16;   // RNE to bf16
    float hf = __uint_as_float(hb << 16);
    float r  = x - hf;
    unsigned rb = __float_as_uint(r);
    unsigned lb = (rb + 0x7FFFu + ((rb >> 16) & 1u)) >> 16;
    h = (ushort)hb; l = (ushort)lb;
}

__device__ __forceinline__ ushort bf16rne(float x) {
    unsigned b = __float_as_uint(x);
    return (ushort)((b + 0x7FFFu + ((b >> 16) & 1u)) >> 16);
}

// ---------------- elementwise split: x -> xh, xl (+ zero hist) ----------------
__global__ __launch_bounds__(256) void k_xsplit(const float* __restrict__ x,
                                                ushort* __restrict__ xh,
                                                ushort* __restrict__ xl, int n,
                                                unsigned* __restrict__ hist) {
    int g = blockIdx.x * 256 + threadIdx.x;
    if (g < BH * NBIN) hist[g] = 0u;
    int i = g * 4;
    if (i >= n) return;
    float4 v = *(const float4*)(x + i);
    ushort4 h, l;
    split1(v.x, h.x, l.x); split1(v.y, h.y, l.y);
    split1(v.z, h.z, l.z); split1(v.w, h.w, l.w);
    *(ushort4*)(xh + i) = h;
    *(ushort4*)(xl + i) = l;
}

// ---------------- transpose + split: W[K][N] -> Wt_h/Wt_l [N][K] ----------------
__global__ __launch_bounds__(256) void k_wsplit(const float* __restrict__ W,
                                                ushort* __restrict__ Wth,
                                                ushort* __restrict__ Wtl,
                                                int K, int N) {
    __shared__ float t[64][65];
    int k0 = blockIdx.y * 64, n0 = blockIdx.x * 64;
    int tid = threadIdx.x;
    int r = tid >> 4, c = (tid & 15) * 4;
#pragma unroll
    for (int u = 0; u < 4; u++) {
        int rr = r + u * 16;
        float4 v = *(const float4*)(W + (size_t)(k0 + rr) * N + n0 + c);
        t[rr][c] = v.x; t[rr][c + 1] = v.y; t[rr][c + 2] = v.z; t[rr][c + 3] = v.w;
    }
    __syncthreads();
    int n = tid >> 2, kc = (tid & 3) * 16;
    ushort hb[16] __attribute__((aligned(16)));
    ushort lb[16] __attribute__((aligned(16)));
#pragma unroll
    for (int j = 0; j < 16; j++) split1(t[kc + j][n], hb[j], lb[j]);
    ushort* dh = Wth + (size_t)(n0 + n) * K + k0 + kc;
    ushort* dl = Wtl + (size_t)(n0 + n) * K + k0 + kc;
    *(uint4*)(dh)     = *(uint4*)&hb[0];
    *(uint4*)(dh + 8) = *(uint4*)&hb[8];
    *(uint4*)(dl)     = *(uint4*)&lb[0];
    *(uint4*)(dl + 8) = *(uint4*)&lb[8];
}

// ======================================================================
// Pipelined bf16x3 GEMM core: BM=64, BN=128, BK=32, 256 thr (r6 core).
// ======================================================================
#define GEMM_CORE_SETUP(Kdim)                                                   \
    __shared__ ushort sA[2][2][64 * 32];                                        \
    __shared__ ushort sB[2][2][128 * 32];                                       \
    int tid = threadIdx.x, lane = tid & 63, wave = tid >> 6;                    \
    int wm = (wave >> 1) * 32, wn = (wave & 1) * 64;                            \
    int l15 = lane & 15, q = lane >> 4;                                         \
    int sr = tid >> 2, sc = tid & 3;                                            \
    const int K = (Kdim);                                                       \
    const ushort* pAh = Ah + (size_t)(m0 + sr) * K + sc * 8;                    \
    const ushort* pAl = Al + (size_t)(m0 + sr) * K + sc * 8;                    \
    const ushort* pBh = Bh + (size_t)(n0 + sr) * K + sc * 8;                    \
    const ushort* pBl = Bl + (size_t)(n0 + sr) * K + sc * 8;                    \
    size_t bstep = (size_t)64 * K;                                              \
    int wA = SWZ(sr, sc), wB2 = SWZ(sr + 64, sc);                               \
    f32x4 acc[2][4] = {};                                                       \
    uint4 rAh = *(const uint4*)(pAh);                                           \
    uint4 rAl = *(const uint4*)(pAl);                                           \
    uint4 rBh0 = *(const uint4*)(pBh);                                          \
    uint4 rBh1 = *(const uint4*)(pBh + bstep);                                  \
    uint4 rBl0 = *(const uint4*)(pBl);                                          \
    uint4 rBl1 = *(const uint4*)(pBl + bstep);                                  \
    *(uint4*)(&sA[0][0][wA])  = rAh;                                            \
    *(uint4*)(&sA[0][1][wA])  = rAl;                                            \
    *(uint4*)(&sB[0][0][wA])  = rBh0;                                           \
    *(uint4*)(&sB[0][0][wB2]) = rBh1;                                           \
    *(uint4*)(&sB[0][1][wA])  = rBl0;                                           \
    *(uint4*)(&sB[0][1][wB2]) = rBl1;                                           \
    __syncthreads();                                                            \
    const int NIT = K / 32;                                                     \
    for (int it = 0; it < NIT; ++it) {                                          \
        int cur = it & 1;                                                       \
        if (it + 1 < NIT) {                                                     \
            int ko = (it + 1) * 32;                                             \
            rAh  = *(const uint4*)(pAh + ko);                                   \
            rAl  = *(const uint4*)(pAl + ko);                                   \
            rBh0 = *(const uint4*)(pBh + ko);                                   \
            rBh1 = *(const uint4*)(pBh + bstep + ko);                           \
            rBl0 = *(const uint4*)(pBl + ko);                                   \
            rBl1 = *(const uint4*)(pBl + bstep + ko);                           \
        }                                                                       \
        bf16x8 fah[2], fal[2], fbh[4], fbl[4];                                  \
        _Pragma("unroll")                                                       \
        for (int mt = 0; mt < 2; mt++) {                                        \
            int rr = wm + mt * 16 + l15;                                        \
            fah[mt] = *(const bf16x8*)(&sA[cur][0][SWZ(rr, q)]);                \
            fal[mt] = *(const bf16x8*)(&sA[cur][1][SWZ(rr, q)]);                \
        }                                                                       \
        _Pragma("unroll")                                                       \
        for (int nt = 0; nt < 4; nt++) {                                        \
            int rr = wn + nt * 16 + l15;                                        \
            fbh[nt] = *(const bf16x8*)(&sB[cur][0][SWZ(rr, q)]);                \
            fbl[nt] = *(const bf16x8*)(&sB[cur][1][SWZ(rr, q)]);                \
        }                                                                       \
        _Pragma("unroll")                                                       \
        for (int mt = 0; mt < 2; mt++)                                          \
            _Pragma("unroll")                                                   \
            for (int nt = 0; nt < 4; nt++) {                                    \
                acc[mt][nt] = __builtin_amdgcn_mfma_f32_16x16x32_bf16(          \
                    fah[mt], fbh[nt], acc[mt][nt], 0, 0, 0);                    \
                acc[mt][nt] = __builtin_amdgcn_mfma_f32_16x16x32_bf16(          \
                    fah[mt], fbl[nt], acc[mt][nt], 0, 0, 0);                    \
                acc[mt][nt] = __builtin_amdgcn_mfma_f32_16x16x32_bf16(          \
                    fal[mt], fbh[nt], acc[mt][nt], 0, 0, 0);                    \
            }                                                                   \
        if (it + 1 < NIT) {                                                     \
            int nxt = cur ^ 1;                                                  \
            *(uint4*)(&sA[nxt][0][wA])  = rAh;                                  \
            *(uint4*)(&sA[nxt][1][wA])  = rAl;                                  \
            *(uint4*)(&sB[nxt][0][wA])  = rBh0;                                 \
            *(uint4*)(&sB[nxt][0][wB2]) = rBh1;                                 \
            *(uint4*)(&sB[nxt][1][wA])  = rBl0;                                 \
            *(uint4*)(&sB[nxt][1][wB2]) = rBl1;                                 \
        }                                                                       \
        __syncthreads();                                                        \
    }

// ---------------- out-proj GEMM: C = A@B + bias (fp32 out) ----------------
__global__ __launch_bounds__(256) void k_gemm_out(
    const ushort* __restrict__ Ah, const ushort* __restrict__ Al,
    const ushort* __restrict__ Bh, const ushort* __restrict__ Bl,
    const float* __restrict__ bias, float* __restrict__ C,
    int M, int N, int Kin) {
    int m0 = blockIdx.y * 64, n0 = blockIdx.x * 128;
    GEMM_CORE_SETUP(Kin)
#pragma unroll
    for (int nt = 0; nt < 4; nt++) {
        int col = n0 + wn + nt * 16 + l15;
        float bv = bias[col];
#pragma unroll
        for (int mt = 0; mt < 2; mt++) {
            int rowb = m0 + wm + mt * 16 + q * 4;
#pragma unroll
            for (int r = 0; r < 4; r++)
                C[(size_t)(rowb + r) * N + col] = acc[mt][nt][r] + bv;
        }
    }
}

// ---------------- QKV GEMM: epilogue writes split Q/K straight + V(hi) transposed
__global__ __launch_bounds__(256) void k_gemm_qkv(
    const ushort* __restrict__ Ah, const ushort* __restrict__ Al,
    const ushort* __restrict__ Bh, const ushort* __restrict__ Bl,
    const float* __restrict__ bias,
    ushort* __restrict__ Qh, ushort* __restrict__ Ql,
    ushort* __restrict__ Kh, ushort* __restrict__ Kl,
    ushort* __restrict__ Vth) {
    int m0 = blockIdx.y * 64, n0 = blockIdx.x * 128;
    GEMM_CORE_SETUP(DMODEL)
    int region = n0 / 768;    // 0=Q, 1=K, 2=V (uniform per block: 128 | 768)
#pragma unroll
    for (int nt = 0; nt < 4; nt++) {
        int col = n0 + wn + nt * 16 + l15;
        float bv = bias[col];
        int cin = col - region * 768;
        int h = cin >> 6, d = cin & 63;
#pragma unroll
        for (int mt = 0; mt < 2; mt++) {
            int rowb = m0 + wm + mt * 16 + q * 4;
            int b = rowb >> 10;
            int s0 = rowb & 1023;
            int bh = b * NHEADS + h;
            if (region == 2) {
                ushort h4[4] __attribute__((aligned(8)));
#pragma unroll
                for (int r = 0; r < 4; r++)
                    h4[r] = bf16rne(acc[mt][nt][r] + bv);
                size_t off = ((size_t)(bh * 64 + d) << 10) + s0;
                *(ushort4*)(Vth + off) = *(ushort4*)h4;
            } else {
                ushort* Ph = region ? Kh : Qh;
                ushort* Pl = region ? Kl : Ql;
                size_t off = ((size_t)((bh << 10) + s0)) * 64 + d;
#pragma unroll
                for (int r = 0; r < 4; r++) {
                    ushort hs, ls;
                    split1(acc[mt][nt][r] + bv, hs, ls);
                    Ph[off + (size_t)r * 64] = hs;
                    Pl[off + (size_t)r * 64] = ls;
                }
            }
        }
    }
}

// ---------------- scores: P = bf16(exp(QK^T/8)) + fused EXACT 4096-bin hist ----
// grid (8, 8, 48). Two-phase epilogue: sP holds 64 rows at a time -> 33 KB LDS
// -> 4 blocks/CU (vs 3 at full-tile sP).
__global__ __launch_bounds__(256) void k_scores(
    const ushort* __restrict__ Qh, const ushort* __restrict__ Ql,
    const ushort* __restrict__ Kh, const ushort* __restrict__ Kl,
    ushort* __restrict__ P, unsigned* __restrict__ hist) {
    __shared__ ushort sP[64 * 132];
    __shared__ unsigned lh[NBIN];
    int bh = blockIdx.z;
    int i0 = blockIdx.y * 128, j0 = blockIdx.x * 128;
    int tid = threadIdx.x, lane = tid & 63, wave = tid >> 6;
    int l15 = lane & 15, q = lane >> 4;
    int wm = (wave >> 1) * 64, wn = (wave & 1) * 64;
    for (int i = tid; i < NBIN; i += 256) lh[i] = 0u;

    const ushort* qb  = Qh + (((size_t)bh << 10)) * 64;
    const ushort* qlb = Ql + (((size_t)bh << 10)) * 64;
    const ushort* kb  = Kh + (((size_t)bh << 10)) * 64;
    const ushort* klb = Kl + (((size_t)bh << 10)) * 64;

    f32x4 acc[4][4] = {};
#pragma unroll
    for (int kk = 0; kk < 64; kk += 32) {
        bf16x8 fqh[4], fql[4], fkh[4], fkl[4];
#pragma unroll
        for (int mt = 0; mt < 4; mt++) {
            size_t off = (size_t)(i0 + wm + mt * 16 + l15) * 64 + kk + q * 8;
            fqh[mt] = *(const bf16x8*)(qb + off);
            fql[mt] = *(const bf16x8*)(qlb + off);
        }
#pragma unroll
        for (int nt = 0; nt < 4; nt++) {
            size_t off = (size_t)(j0 + wn + nt * 16 + l15) * 64 + kk + q * 8;
            fkh[nt] = *(const bf16x8*)(kb + off);
            fkl[nt] = *(const bf16x8*)(klb + off);
        }
#pragma unroll
        for (int mt = 0; mt < 4; mt++)
#pragma unroll
            for (int nt = 0; nt < 4; nt++) {
                acc[mt][nt] = __builtin_amdgcn_mfma_f32_16x16x32_bf16(
                    fqh[mt], fkh[nt], acc[mt][nt], 0, 0, 0);
                acc[mt][nt] = __builtin_amdgcn_mfma_f32_16x16x32_bf16(
                    fqh[mt], fkl[nt], acc[mt][nt], 0, 0, 0);
                acc[mt][nt] = __builtin_amdgcn_mfma_f32_16x16x32_bf16(
                    fql[mt], fkh[nt], acc[mt][nt], 0, 0, 0);
            }
    }
    __syncthreads();   // MFMA done + lh zeroed by all before atomics

    // two-phase epilogue: phase ph handles mt = {2ph, 2ph+1}
    //   global row = (wave>>1)*64 + ph*32 + m2*16 + q*4 + r2
    //   local  row = (wave>>1)*32 +          m2*16 + q*4 + r2  (0..63)
#pragma unroll
    for (int ph = 0; ph < 2; ph++) {
#pragma unroll
        for (int m2 = 0; m2 < 2; m2++) {
            int mt = ph * 2 + m2;
            int lrow0 = (wave >> 1) * 32 + m2 * 16 + q * 4;
#pragma unroll
            for (int nt = 0; nt < 4; nt++) {
                int jj = wn + nt * 16 + l15;
#pragma unroll
                for (int r2 = 0; r2 < 4; r2++) {
                    ushort pb = bf16rne(__expf(acc[mt][nt][r2] * 0.125f));
                    sP[(lrow0 + r2) * 132 + jj] = pb;
                    int bin = (int)pb - BIN0;
                    bin = (bin < 0) ? 0 : ((bin > NBIN - 1) ? NBIN - 1 : bin);
                    atomicAdd(&lh[bin], 1u);
                }
            }
        }
        __syncthreads();
        // coalesced writeout: 4 threads per local row, 32 cols each
        int rloc = tid >> 2;
        int ch = (tid & 3) * 32;
        int grow = i0 + (rloc & 31) + ph * 32 + (rloc >> 5) * 64;
        ushort* dst = P + ((size_t)bh << 20) + (size_t)grow * 1024 + j0 + ch;
        const ushort* src = sP + rloc * 132 + ch;
#pragma unroll
        for (int c = 0; c < 4; c++)
            *(uint4*)(dst + c * 8) = *(const uint4*)(src + c * 8);
        if (ph == 0) __syncthreads();   // sP reused by phase 1
    }
    for (int i = tid; i < NBIN; i += 256) {
        unsigned cc = lh[i];
        if (cc) atomicAdd(&hist[bh * NBIN + i], cc);
    }
}

// ---------------- select: scan 4096 bins -> exact bf16 threshold pattern -------
__global__ void k_select(const unsigned* __restrict__ hist,
                         unsigned* __restrict__ thrb) {
    int bh = blockIdx.x;
    const unsigned* hrow = hist + bh * NBIN;
    __shared__ unsigned ps[256];
    int tid = threadIdx.x;
    unsigned s = 0;
#pragma unroll
    for (int i = 0; i < 16; i++) s += hrow[tid * 16 + i];
    ps[tid] = s;
    __syncthreads();
    if (tid == 0) {
        unsigned k = KTH, run = 0; int chunk = 255;
        for (int t2 = 0; t2 < 256; t2++) {
            if (run + ps[t2] >= k) { chunk = t2; break; }
            run += ps[t2];
        }
        int d = 15;
        for (int i = 0; i < 16; i++) {
            unsigned v = hrow[chunk * 16 + i];
            if (run + v >= k) { d = i; break; }
            run += v;
        }
        thrb[bh] = (unsigned)(BIN0 + chunk * 16 + d);
    }
}

// ---------------- PV: ctx = (masked P) @ Vh / rowsum ---------------------------
// grid (64, 48): 16 rows per block; 4 waves split the j-axis (256 each);
// LDS cross-wave reduction.
__global__ __launch_bounds__(256) void k_pv(const ushort* __restrict__ P,
                                            const ushort* __restrict__ Vth,
                                            const unsigned* __restrict__ thrb,
                                            ushort* __restrict__ ctxh,
                                            ushort* __restrict__ ctxl) {
    __shared__ float sred[4 * 1280];   // [wave][ (acc_idx*4+r)*64 + lane ]
    int bh = blockIdx.y;
    int b = bh / NHEADS, h = bh % NHEADS;
    int lane = threadIdx.x & 63, wave = threadIdx.x >> 6;
    int l15 = lane & 15, q = lane >> 4;
    int ibase = blockIdx.x * 16;
    unsigned t = thrb[bh];
    const ushort* prow = P + ((size_t)bh << 20) + (size_t)(ibase + l15) * 1024 + q * 8;
    const ushort* vh0 = Vth + ((size_t)bh << 16);   // [64][1024]
    f32x4 acc[4] = {};
    f32x4 lacc = {};
    uint4 onesu = {0x3F803F80u, 0x3F803F80u, 0x3F803F80u, 0x3F803F80u};
    bf16x8 ones = *(bf16x8*)&onesu;
    int jw = wave * 256;
#pragma unroll 2
    for (int j0 = jw; j0 < jw + 256; j0 += 32) {
        uint4 a = *(const uint4*)(prow + j0);
        unsigned* w = (unsigned*)&a;
#pragma unroll
        for (int e = 0; e < 4; e++) {
            unsigned lo = w[e] & 0xFFFFu, hi = w[e] >> 16;
            lo = (lo <= t) ? 0u : lo;
            hi = (hi <= t) ? 0u : hi;
            w[e] = lo | (hi << 16);
        }
        bf16x8 pa = *(bf16x8*)&a;
#pragma unroll
        for (int nt = 0; nt < 4; nt++) {
            size_t off = (size_t)(nt * 16 + l15) * 1024 + j0 + q * 8;
            bf16x8 fvh = *(const bf16x8*)(vh0 + off);
            acc[nt] = __builtin_amdgcn_mfma_f32_16x16x32_bf16(pa, fvh, acc[nt], 0, 0, 0);
        }
        lacc = __builtin_amdgcn_mfma_f32_16x16x32_bf16(pa, ones, lacc, 0, 0, 0);
    }
    float* my = sred + wave * 1280;
#pragma unroll
    for (int nt = 0; nt < 4; nt++)
#pragma unroll
        for (int r = 0; r < 4; r++)
            my[(nt * 4 + r) * 64 + lane] = acc[nt][r];
#pragma unroll
    for (int r = 0; r < 4; r++)
        my[(16 + r) * 64 + lane] = lacc[r];
    __syncthreads();
    for (int f = threadIdx.x; f < 1280; f += 256)
        sred[f] = sred[f] + sred[1280 + f] + sred[2560 + f] + sred[3840 + f];
    __syncthreads();
#pragma unroll
    for (int r = 0; r < 4; r++) {
        int i = ibase + q * 4 + r;
        float l = sred[(16 + r) * 64 + lane];
        float v = sred[(wave * 4 + r) * 64 + lane];
        int d = wave * 16 + l15;
        ushort hs, ls;
        split1(v / l, hs, ls);
        size_t off = ((size_t)(b * SEQ + i)) * DMODEL + h * 64 + d;
        ctxh[off] = hs;
        ctxl[off] = ls;
    }
}

extern "C" void kernel_launch(void* const* d_in, const int* in_sizes, int n_in,
                              void* d_out, int out_size, void* d_ws, size_t ws_size,
                              hipStream_t stream) {
    const float* x    = (const float*)d_in[0];
    const float* Wqkv = (const float*)d_in[1];
    const float* bqkv = (const float*)d_in[2];
    const float* Wout = (const float*)d_in[3];
    const float* bout = (const float*)d_in[4];
    float* out = (float*)d_out;

    char* ws = (char*)d_ws;
    // persistent layout
    ushort* Qh  = (ushort*)(ws + 0);                 //  6,291,456
    ushort* Ql  = (ushort*)(ws + 6291456);
    ushort* Kh  = (ushort*)(ws + 12582912);
    ushort* Kl  = (ushort*)(ws + 18874368);
    ushort* Vth = (ushort*)(ws + 25165824);          //  6,291,456 (hi only)
    ushort* P   = (ushort*)(ws + 37748736);          // 100,663,296 -> ends 138,412,032
    ushort* ctxh = (ushort*)(ws + 239075328);        //  6,291,456
    ushort* ctxl = (ushort*)(ws + 245366784);        // ends 251,658,240
    unsigned* hist = (unsigned*)(ws + 251658240);    // 48*4096*4 = 786,432
    unsigned* thrb = (unsigned*)(ws + 252444672);    // 192
    // overlays inside P region (dead until k_scores writes P):
    ushort* xh     = (ushort*)(ws + 37748736);
    ushort* xl     = (ushort*)(ws + 37748736 + 6291456);
    ushort* Wqkvth = (ushort*)(ws + 37748736 + 12582912);
    ushort* Wqkvtl = (ushort*)(ws + 37748736 + 16121856);
    // Wout split overlays P (dead after k_pv):
    ushort* Woutth = (ushort*)(ws + 37748736);
    ushort* Wouttl = (ushort*)(ws + 37748736 + 1179648);

    // split x (+ zero hist: 196,608 slots <= 786,432 threads)
    k_xsplit<<<NTOK * DMODEL / 1024, 256, 0, stream>>>(x, xh, xl, NTOK * DMODEL, hist);
    k_wsplit<<<dim3(D3 / 64, DMODEL / 64), 256, 0, stream>>>(Wqkv, Wqkvth, Wqkvtl, DMODEL, D3);
    k_gemm_qkv<<<dim3(D3 / 128, NTOK / 64), 256, 0, stream>>>(
        xh, xl, Wqkvth, Wqkvtl, bqkv, Qh, Ql, Kh, Kl, Vth);
    // P = bf16(exp(QK^T/8)) + fused exact 4096-bin histogram
    k_scores<<<dim3(8, 8, BH), 256, 0, stream>>>(Qh, Ql, Kh, Kl, P, hist);
    k_select<<<BH, 256, 0, stream>>>(hist, thrb);
    // ctx = masked-softmax(P) @ V
    k_pv<<<dim3(64, BH), 256, 0, stream>>>(P, Vth, thrb, ctxh, ctxl);
    // out = ctx @ W_out + b_out
    k_wsplit<<<dim3(DMODEL / 64, DMODEL / 64), 256, 0, stream>>>(Wout, Woutth, Wouttl, DMODEL, DMODEL);
    k_gemm_out<<<dim3(DMODEL / 128, NTOK / 64), 256, 0, stream>>>(
        ctxh, ctxl, Woutth, Wouttl, bout, out, NTOK, DMODEL, DMODEL);
}